// Round 5
// baseline (287.968 us; speedup 1.0000x reference)
//
#include <hip/hip_runtime.h>
#include <math.h>

#define B_   8
#define C_   256
#define CI_  128
#define N_   4096

typedef unsigned short ushort_t;
typedef unsigned int uint_t;
typedef __attribute__((ext_vector_type(8))) short short8;
typedef __attribute__((ext_vector_type(16))) float floatx16;

// workspace layout (byte offsets)
#define OFF_W3B  0ull           // bf16 [384][256]
#define OFF_B3   196608ull      // fp32 [384]
#define OFF_WCB  198144ull      // bf16 [256][128]
#define OFF_XT   263680ull      // bf16 [B][N][256]   16.8 MB
#define OFF_THT  17040896ull    // bf16 [B][N][128]   8.4 MB
#define OFF_PHT  25429504ull    // bf16 [B][N][128]   8.4 MB
#define OFF_G16  33818112ull    // bf16 [B][128][N]   8.4 MB
#define OFF_LP   42206720ull    // fp32 [2][B][N]     256 KB
#define OFF_YPB  42468864ull    // bf16 [2][B][N][128] 16.8 MB
#define OFF_YTB  59246080ull    // bf16 [B][N][128]   8.4 MB
#define OFF_WY   263680ull      // fp32 [B][256][N] — aliases XT+THT+PHT (dead after attn)
#define OFF_ST   67634688ull    // fp32 [2][256]
// total ~67.6 MB

__device__ __forceinline__ ushort_t f2bf(float x) {
  union { float f; uint_t u; } c; c.f = x;
  return (ushort_t)((c.u + 0x7fffu + ((c.u >> 16) & 1u)) >> 16);
}
__device__ __forceinline__ uint_t pack_bf2(float a, float b) {
  union { float f; uint_t u; } x, y; x.f = a; y.f = b;
  uint_t lo = (x.u + 0x7fffu + ((x.u >> 16) & 1u)) >> 16;
  uint_t hi = (y.u + 0x7fffu + ((y.u >> 16) & 1u)) & 0xffff0000u;
  return lo | hi;
}
__device__ __forceinline__ float bf_lo(uint_t u) {
  union { uint_t u; float f; } c; c.u = u << 16; return c.f;
}
__device__ __forceinline__ float bf_hi(uint_t u) {
  union { uint_t u; float f; } c; c.u = u & 0xffff0000u; return c.f;
}
__device__ __forceinline__ void async_copy16(const void* g, void* l) {
  __builtin_amdgcn_global_load_lds(
      (const __attribute__((address_space(1))) unsigned int*)g,
      (__attribute__((address_space(3))) unsigned int*)l, 16, 0, 0);
}

// -------- pack weights: [g|theta|phi] -> bf16 [384][256] + fp32 bias[384] ----
__global__ __launch_bounds__(256) void pack_w(
    const float* __restrict__ g_w, const float* __restrict__ g_b,
    const float* __restrict__ th_w, const float* __restrict__ th_b,
    const float* __restrict__ ph_w, const float* __restrict__ ph_b,
    ushort_t* __restrict__ W3b, float* __restrict__ b3)
{
  int i = blockIdx.x * 256 + threadIdx.x;
  int o = i >> 8;
  float v;
  if (o < 128)      v = g_w[i];
  else if (o < 256) v = th_w[i - 128*256];
  else              v = ph_w[i - 256*256];
  W3b[i] = f2bf(v);
  if ((i & 255) == 0)
    b3[o] = (o < 128) ? g_b[o] : (o < 256) ? th_b[o - 128] : ph_b[o - 256];
}

// -------- W conv weight -> bf16 [256][128] ----------------------------------
__global__ __launch_bounds__(256) void wpack(
    const float* __restrict__ W_w, ushort_t* __restrict__ Wc)
{
  int i = blockIdx.x * 256 + threadIdx.x;   // < 32768
  Wc[i] = f2bf(W_w[i]);
}

// -------- x [b][c][n] fp32 -> xt [b][n][c] bf16 (64x64 LDS transpose) -------
__global__ __launch_bounds__(256) void xcast(
    const float* __restrict__ x, ushort_t* __restrict__ xt)
{
  const int b = blockIdx.z, c0 = blockIdx.y * 64, n0 = blockIdx.x * 64;
  const int tid = threadIdx.x;
  __shared__ float xs[64][65];
  const int nq = (tid & 15) * 4, cr = tid >> 4;
  #pragma unroll
  for (int i = 0; i < 4; ++i) {
    float4 v = *(const float4*)&x[((size_t)b * C_ + c0 + cr + 16*i) * N_ + n0 + nq];
    xs[cr + 16*i][nq] = v.x; xs[cr + 16*i][nq+1] = v.y;
    xs[cr + 16*i][nq+2] = v.z; xs[cr + 16*i][nq+3] = v.w;
  }
  __syncthreads();
  const int n = tid >> 2, cs = (tid & 3) * 16;
  uint_t u[8];
  #pragma unroll
  for (int j = 0; j < 8; ++j)
    u[j] = pack_bf2(xs[cs + 2*j][n], xs[cs + 2*j + 1][n]);
  ushort_t* dst = &xt[((size_t)b * N_ + n0 + n) * C_ + c0 + cs];
  *(uint4*)dst       = make_uint4(u[0], u[1], u[2], u[3]);
  *(uint4*)(dst + 8) = make_uint4(u[4], u[5], u[6], u[7]);
}

// -------- projection GEMM, bf16 MFMA 32x32x16 (proven in round 4) -----------
template<int GMODE>
__global__ __launch_bounds__(256, 2) void proj_mfma(
    const ushort_t* __restrict__ W3b, const float* __restrict__ b3,
    const ushort_t* __restrict__ xt, ushort_t* __restrict__ tht,
    ushort_t* __restrict__ pht, ushort_t* __restrict__ g16)
{
  const int b = blockIdx.z, nb = blockIdx.x, ot = blockIdx.y;
  const int o0 = GMODE ? 0 : (128 + ot * 128);
  const int tid = threadIdx.x, w = tid >> 6, lane = tid & 63;
  const int l31 = lane & 31, h = lane >> 5, xk = l31 & 7;
  __shared__ ushort_t ws_l[128 * 64];
  __shared__ ushort_t xs_l[128 * 64];
  const ushort_t* xb = xt + (size_t)b * N_ * C_;
  const int n0 = nb * 128;
  floatx16 acc[4];
  #pragma unroll
  for (int ct = 0; ct < 4; ++ct)
    #pragma unroll
    for (int r = 0; r < 16; ++r) acc[ct][r] = 0.f;

  const int gr = lane >> 3, gu = lane & 7;
  for (int k0 = 0; k0 < C_; k0 += 64) {
    __syncthreads();
    #pragma unroll
    for (int i = 0; i < 4; ++i) {
      int r = w*32 + i*8 + gr;
      async_copy16(&W3b[(size_t)(o0 + r) * C_ + k0 + ((gu ^ (r & 7)) * 8)],
                   &ws_l[(w*32 + i*8) * 64]);
      async_copy16(&xb[(size_t)(n0 + r) * C_ + k0 + ((gu ^ (r & 7)) * 8)],
                   &xs_l[(w*32 + i*8) * 64]);
    }
    __syncthreads();
    #pragma unroll
    for (int kk = 0; kk < 4; ++kk) {
      int fc = ((2*kk + h) ^ xk) * 8;
      short8 bf = GMODE ? *(const short8*)&ws_l[(w*32 + l31) * 64 + fc]
                        : *(const short8*)&xs_l[(w*32 + l31) * 64 + fc];
      #pragma unroll
      for (int ct = 0; ct < 4; ++ct) {
        short8 af = GMODE ? *(const short8*)&xs_l[(ct*32 + l31) * 64 + fc]
                          : *(const short8*)&ws_l[(ct*32 + l31) * 64 + fc];
        acc[ct] = __builtin_amdgcn_mfma_f32_32x32x16_bf16(af, bf, acc[ct], 0, 0, 0);
      }
    }
  }

  if (GMODE) {
    float bv = b3[w*32 + l31];
    ushort_t* gp = g16 + ((size_t)b * CI_ + w*32 + l31) * N_;
    #pragma unroll
    for (int ct = 0; ct < 4; ++ct)
      #pragma unroll
      for (int rq = 0; rq < 4; ++rq) {
        uint2 d = make_uint2(pack_bf2(acc[ct][4*rq+0] + bv, acc[ct][4*rq+1] + bv),
                             pack_bf2(acc[ct][4*rq+2] + bv, acc[ct][4*rq+3] + bv));
        *(uint2*)&gp[n0 + ct*32 + 8*rq + 4*h] = d;
      }
  } else {
    ushort_t* tp = ((ot == 0) ? tht : pht) + ((size_t)b * N_ + n0 + w*32 + l31) * CI_;
    #pragma unroll
    for (int ct = 0; ct < 4; ++ct)
      #pragma unroll
      for (int rq = 0; rq < 4; ++rq) {
        float4 bv = *(const float4*)&b3[o0 + ct*32 + 8*rq + 4*h];
        uint2 d = make_uint2(pack_bf2(acc[ct][4*rq+0] + bv.x, acc[ct][4*rq+1] + bv.y),
                             pack_bf2(acc[ct][4*rq+2] + bv.z, acc[ct][4*rq+3] + bv.w));
        *(uint2*)&tp[ct*32 + 8*rq + 4*h] = d;
      }
  }
}

// ---------------------------------------------------------------------------
// MFMA flash attention v3: 2 q-tiles/wave (64 q), 4 waves = 256 q per block.
// 512-VGPR cap (launch_bounds(256,1)) -> no spill; 96 KB LDS, 1 block/CU,
// grid 256 fully resident. Double-buffered DMA staging, 1 barrier/iter.
// Epilogue: in-LDS transpose -> bf16 partials yp[ms][b][q][c].
// ---------------------------------------------------------------------------
#define LOG2E_  1.442695041f
#define MBIAS_  (-28.85390082f)   /* = -20 * log2(e) */

__global__ __launch_bounds__(256, 1) void attn_mfma(
    const ushort_t* __restrict__ tht, const ushort_t* __restrict__ pht,
    const ushort_t* __restrict__ g16, ushort_t* __restrict__ yp,
    float* __restrict__ lp)
{
  const int b  = blockIdx.x & 7;           // batch -> XCD
  const int ms = (blockIdx.x >> 3) & 1;    // key split
  const int qb = blockIdx.x >> 4;          // 0..15
  const int tid = threadIdx.x, w = tid >> 6, lane = tid & 63;
  const int l31 = lane & 31, h = lane >> 5, xk = l31 & 7;

  // smem map (ushort idx): phs[buf] @ buf*8192 (64x128); gs[buf] @ 16384+buf*8192
  // (128x64); Pl[w][qt] @ 32768+(w*2+qt)*2048 (32x64). 96 KB total.
  __shared__ ushort_t smem[49152];

  const int q0w = qb * 256 + w * 64;
  const int m_base = ms * 2048;

  const ushort_t* thb = tht + (size_t)b * N_ * CI_;
  const ushort_t* phb = pht + (size_t)b * N_ * CI_;
  const ushort_t* gbp = g16 + (size_t)b * CI_ * N_;

  // theta B-frags, register-resident (lane: col q = qt*32+l31, k contig)
  short8 tf[2][8];
  #pragma unroll
  for (int qt = 0; qt < 2; ++qt)
    #pragma unroll
    for (int kk = 0; kk < 8; ++kk)
      tf[qt][kk] = *(const short8*)&thb[(size_t)(q0w + qt*32 + l31) * CI_ + kk*16 + h*8];

  floatx16 acc[2][4];
  #pragma unroll
  for (int qt = 0; qt < 2; ++qt)
    #pragma unroll
    for (int ct = 0; ct < 4; ++ct)
      #pragma unroll
      for (int r = 0; r < 16; ++r) acc[qt][ct][r] = 0.f;
  float lpart[2] = {0.f, 0.f};

  const int pRow = lane >> 4, pCol = lane & 15;   // phi staging coords
  const int gRow = lane >> 3, gCol = lane & 7;    // g staging coords

  auto stage = [&](int m0, int buf) {
    ushort_t* phd = smem + buf * 8192;
    ushort_t* gd  = smem + 16384 + buf * 8192;
    #pragma unroll
    for (int i = 0; i < 4; ++i) {
      int rb = i*16 + w*4;
      int row = rb + pRow;
      async_copy16(&phb[(size_t)(m0 + row) * CI_ + ((pCol ^ (row & 7)) * 8)],
                   phd + rb * 128);
    }
    #pragma unroll
    for (int i = 0; i < 4; ++i) {
      int rb = i*32 + w*8;
      int row = rb + gRow;
      async_copy16(&gbp[(size_t)row * N_ + m0 + ((gCol ^ (row & 7)) * 8)],
                   gd + rb * 64);
    }
  };

  stage(m_base, 0);

  for (int it = 0; it < 32; ++it) {
    const int buf = it & 1;
    __syncthreads();   // own DMA(it) drained before barrier; buf[1-cur] readers done
    if (it + 1 < 32) stage(m_base + (it + 1) * 64, buf ^ 1);

    const ushort_t* phs = smem + buf * 8192;
    const ushort_t* gs  = smem + 16384 + buf * 8192;
    ushort_t* Pl0 = smem + 32768 + (w*2 + 0) * 2048;
    ushort_t* Pl1 = smem + 32768 + (w*2 + 1) * 2048;

    // QK^T + exp + P pack (lane = col q fixed -> softmax lane-local)
    #pragma unroll
    for (int mt = 0; mt < 2; ++mt) {
      floatx16 s0, s1;
      #pragma unroll
      for (int r = 0; r < 16; ++r) { s0[r] = 0.f; s1[r] = 0.f; }
      #pragma unroll
      for (int kk = 0; kk < 8; ++kk) {
        short8 pf = *(const short8*)&phs[(mt*32 + l31) * 128 + (((2*kk + h) ^ xk) * 8)];
        s0 = __builtin_amdgcn_mfma_f32_32x32x16_bf16(pf, tf[0][kk], s0, 0, 0, 0);
        s1 = __builtin_amdgcn_mfma_f32_32x32x16_bf16(pf, tf[1][kk], s1, 0, 0, 0);
      }
      #pragma unroll
      for (int qt = 0; qt < 2; ++qt) {
        const floatx16& s = qt ? s1 : s0;
        ushort_t* Pq = qt ? Pl1 : Pl0;
        float ls = 0.f;
        #pragma unroll
        for (int rq = 0; rq < 4; ++rq) {
          float p0 = exp2f(fmaf(s[4*rq+0], LOG2E_, MBIAS_));
          float p1 = exp2f(fmaf(s[4*rq+1], LOG2E_, MBIAS_));
          float p2 = exp2f(fmaf(s[4*rq+2], LOG2E_, MBIAS_));
          float p3 = exp2f(fmaf(s[4*rq+3], LOG2E_, MBIAS_));
          ls += (p0 + p1) + (p2 + p3);
          uint2 d = make_uint2(pack_bf2(p0, p1), pack_bf2(p2, p3));
          *(uint2*)&Pq[l31 * 64 + (((mt*4 + rq) ^ xk) * 8) + h*4] = d;
        }
        lpart[qt] += ls;
      }
    }

    // PV: y^T[c][q] += g[c][m] . P[m][q]; g fragments shared across both qt
    #pragma unroll
    for (int kk = 0; kk < 4; ++kk) {
      int pc = ((2*kk + h) ^ xk) * 8;
      short8 p0 = *(const short8*)&Pl0[l31 * 64 + pc];
      short8 p1 = *(const short8*)&Pl1[l31 * 64 + pc];
      #pragma unroll
      for (int ct = 0; ct < 4; ++ct) {
        short8 gf = *(const short8*)&gs[(ct*32 + l31) * 64 + pc];
        acc[0][ct] = __builtin_amdgcn_mfma_f32_32x32x16_bf16(gf, p0, acc[0][ct], 0, 0, 0);
        acc[1][ct] = __builtin_amdgcn_mfma_f32_32x32x16_bf16(gf, p1, acc[1][ct], 0, 0, 0);
      }
    }
  }

  // l partials
  #pragma unroll
  for (int qt = 0; qt < 2; ++qt) {
    float lq = lpart[qt] + __shfl_xor(lpart[qt], 32);
    if (h == 0)
      lp[((size_t)ms * 8 + b) * N_ + q0w + qt*32 + l31] = lq;
  }

  // epilogue: in-LDS transpose (wave-private 16 KB region) -> bf16 [q][c]
  __syncthreads();   // all waves done reading phs/gs before overwrite
  ushort_t* tr = smem + w * 8192;   // 64 rows(q) x 128 (c)
  #pragma unroll
  for (int qt = 0; qt < 2; ++qt)
    #pragma unroll
    for (int ct = 0; ct < 4; ++ct)
      #pragma unroll
      for (int rq = 0; rq < 4; ++rq) {
        uint2 d = make_uint2(pack_bf2(acc[qt][ct][4*rq+0], acc[qt][ct][4*rq+1]),
                             pack_bf2(acc[qt][ct][4*rq+2], acc[qt][ct][4*rq+3]));
        *(uint2*)&tr[(qt*32 + l31) * 128 + ct*32 + 8*rq + 4*h] = d;
      }
  // same-wave LDS ordering: no barrier needed between write and read
  ushort_t* ypb = yp + (((size_t)ms * 8 + b) * N_ + q0w) * CI_;
  #pragma unroll
  for (int itx = 0; itx < 16; ++itx) {
    int row = itx*4 + (lane >> 4);
    int cu  = (lane & 15) * 8;
    uint4 v = *(const uint4*)&tr[row * 128 + cu];
    *(uint4*)&ypb[(size_t)row * CI_ + cu] = v;
  }
}

// -------- combine: ytb[b][q][c] = (yp0 + yp1) / (l0 + l1), bf16 out ---------
__global__ __launch_bounds__(256) void combine(
    const ushort_t* __restrict__ yp, const float* __restrict__ lp,
    ushort_t* __restrict__ ytb)
{
  size_t idx = (size_t)blockIdx.x * 256 + threadIdx.x;   // uint4 index
  size_t i = idx * 8;                                    // element index
  int q_lin = (int)(i >> 7);
  const size_t halfU = (size_t)B_ * N_ * CI_ / 8;
  uint4 a = ((const uint4*)yp)[idx];
  uint4 c = ((const uint4*)yp)[halfU + idx];
  float inv = 1.0f / (lp[q_lin] + lp[(size_t)B_ * N_ + q_lin]);
  uint4 o;
  o.x = pack_bf2((bf_lo(a.x) + bf_lo(c.x)) * inv, (bf_hi(a.x) + bf_hi(c.x)) * inv);
  o.y = pack_bf2((bf_lo(a.y) + bf_lo(c.y)) * inv, (bf_hi(a.y) + bf_hi(c.y)) * inv);
  o.z = pack_bf2((bf_lo(a.z) + bf_lo(c.z)) * inv, (bf_hi(a.z) + bf_hi(c.z)) * inv);
  o.w = pack_bf2((bf_lo(a.w) + bf_lo(c.w)) * inv, (bf_hi(a.w) + bf_hi(c.w)) * inv);
  ((uint4*)ytb)[idx] = o;
}

// -------- W-conv GEMM, bf16 MFMA: WY[b][o][n] = sum_c Wc[o][c] ytb[b][n][c] -
__global__ __launch_bounds__(256, 2) void wgemm_mfma(
    const ushort_t* __restrict__ Wc, const float* __restrict__ Wb,
    const ushort_t* __restrict__ ytb, float* __restrict__ WY)
{
  const int b = blockIdx.z, nb = blockIdx.x, ot = blockIdx.y;
  const int o0 = ot * 128;
  const int tid = threadIdx.x, w = tid >> 6, lane = tid & 63;
  const int l31 = lane & 31, h = lane >> 5, xk = l31 & 7;
  __shared__ ushort_t ws_l[128 * 64];
  __shared__ ushort_t xs_l[128 * 64];
  const ushort_t* xb = ytb + (size_t)b * N_ * CI_;
  const int n0 = nb * 128;
  floatx16 acc[4];
  #pragma unroll
  for (int ct = 0; ct < 4; ++ct)
    #pragma unroll
    for (int r = 0; r < 16; ++r) acc[ct][r] = 0.f;

  const int gr = lane >> 3, gu = lane & 7;
  for (int k0 = 0; k0 < CI_; k0 += 64) {
    __syncthreads();
    #pragma unroll
    for (int i = 0; i < 4; ++i) {
      int r = w*32 + i*8 + gr;
      async_copy16(&Wc[(size_t)(o0 + r) * CI_ + k0 + ((gu ^ (r & 7)) * 8)],
                   &ws_l[(w*32 + i*8) * 64]);
      async_copy16(&xb[(size_t)(n0 + r) * CI_ + k0 + ((gu ^ (r & 7)) * 8)],
                   &xs_l[(w*32 + i*8) * 64]);
    }
    __syncthreads();
    #pragma unroll
    for (int kk = 0; kk < 4; ++kk) {
      int fc = ((2*kk + h) ^ xk) * 8;
      short8 bf = *(const short8*)&xs_l[(w*32 + l31) * 64 + fc];
      #pragma unroll
      for (int ct = 0; ct < 4; ++ct) {
        short8 af = *(const short8*)&ws_l[(ct*32 + l31) * 64 + fc];
        acc[ct] = __builtin_amdgcn_mfma_f32_32x32x16_bf16(af, bf, acc[ct], 0, 0, 0);
      }
    }
  }
  const int n = n0 + w*32 + l31;
  #pragma unroll
  for (int ct = 0; ct < 4; ++ct)
    #pragma unroll
    for (int rq = 0; rq < 4; ++rq) {
      float4 bv = *(const float4*)&Wb[o0 + ct*32 + 8*rq + 4*h];
      #pragma unroll
      for (int j = 0; j < 4; ++j) {
        int o = o0 + ct*32 + 8*rq + 4*h + j;
        WY[((size_t)b * C_ + o) * N_ + n] = acc[ct][4*rq + j] + (&bv.x)[j];
      }
    }
}

__global__ __launch_bounds__(256) void bn_stats(
    const float* __restrict__ WY, float* __restrict__ st)
{
  const int o = blockIdx.x;
  const int tid = threadIdx.x;
  float s = 0.f, s2 = 0.f;
  for (int b = 0; b < B_; ++b) {
    const float* p = WY + ((size_t)b * C_ + o) * N_;
    for (int n = tid * 4; n < N_; n += 256 * 4) {
      float4 v = *(const float4*)&p[n];
      s  += v.x + v.y + v.z + v.w;
      s2 += v.x * v.x + v.y * v.y + v.z * v.z + v.w * v.w;
    }
  }
  __shared__ float rs[256], rs2[256];
  rs[tid] = s; rs2[tid] = s2;
  __syncthreads();
  for (int off = 128; off > 0; off >>= 1) {
    if (tid < off) { rs[tid] += rs[tid + off]; rs2[tid] += rs2[tid + off]; }
    __syncthreads();
  }
  if (tid == 0) {
    const float M = (float)(B_ * N_);
    float mean = rs[0] / M;
    float var  = rs2[0] / M - mean * mean;
    st[o] = mean;
    st[256 + o] = rsqrtf(var + 1e-5f);
  }
}

__global__ __launch_bounds__(256) void bn_apply(
    const float* __restrict__ WY, const float* __restrict__ x,
    const float* __restrict__ st, const float* __restrict__ gamma,
    const float* __restrict__ beta, float* __restrict__ out)
{
  size_t i = ((size_t)blockIdx.x * 256 + threadIdx.x) * 4;
  int o = (int)((i >> 12) & 255);
  float4 w  = *(const float4*)&WY[i];
  float4 xv = *(const float4*)&x[i];
  float gsc = gamma[o] * st[256 + o];
  float bb  = beta[o] - st[o] * gsc;
  float4 v;
  v.x = w.x * gsc + bb + xv.x;
  v.y = w.y * gsc + bb + xv.y;
  v.z = w.z * gsc + bb + xv.z;
  v.w = w.w * gsc + bb + xv.w;
  *(float4*)&out[i] = v;
}

extern "C" void kernel_launch(void* const* d_in, const int* in_sizes, int n_in,
                              void* d_out, int out_size, void* d_ws, size_t ws_size,
                              hipStream_t stream)
{
  const float* x       = (const float*)d_in[0];
  const float* g_w     = (const float*)d_in[1];
  const float* g_b     = (const float*)d_in[2];
  const float* theta_w = (const float*)d_in[3];
  const float* theta_b = (const float*)d_in[4];
  const float* phi_w   = (const float*)d_in[5];
  const float* phi_b   = (const float*)d_in[6];
  const float* W_w     = (const float*)d_in[7];
  const float* W_b     = (const float*)d_in[8];
  const float* gamma   = (const float*)d_in[9];
  const float* beta    = (const float*)d_in[10];
  float* out = (float*)d_out;

  char* ws = (char*)d_ws;
  ushort_t* W3b = (ushort_t*)(ws + OFF_W3B);
  float*    b3  = (float*)(ws + OFF_B3);
  ushort_t* Wc  = (ushort_t*)(ws + OFF_WCB);
  ushort_t* xt  = (ushort_t*)(ws + OFF_XT);
  ushort_t* tht = (ushort_t*)(ws + OFF_THT);
  ushort_t* pht = (ushort_t*)(ws + OFF_PHT);
  ushort_t* g16 = (ushort_t*)(ws + OFF_G16);
  float*    lpp = (float*)(ws + OFF_LP);
  ushort_t* ypb = (ushort_t*)(ws + OFF_YPB);
  ushort_t* ytb = (ushort_t*)(ws + OFF_YTB);
  float*    WY  = (float*)(ws + OFF_WY);    // aliases XT/THT/PHT (dead by wgemm)
  float*    ST  = (float*)(ws + OFF_ST);

  pack_w<<<384, 256, 0, stream>>>(g_w, g_b, theta_w, theta_b, phi_w, phi_b, W3b, b3);
  wpack<<<128, 256, 0, stream>>>(W_w, Wc);
  xcast<<<dim3(64, 4, 8), 256, 0, stream>>>(x, xt);
  proj_mfma<0><<<dim3(32, 2, 8), 256, 0, stream>>>(W3b, b3, xt, tht, pht, g16);
  proj_mfma<1><<<dim3(32, 1, 8), 256, 0, stream>>>(W3b, b3, xt, tht, pht, g16);
  attn_mfma<<<256, 256, 0, stream>>>(tht, pht, g16, ypb, lpp);
  combine<<<2048, 256, 0, stream>>>(ypb, lpp, ytb);
  wgemm_mfma<<<dim3(32, 2, 8), 256, 0, stream>>>(Wc, W_b, ytb, WY);
  bn_stats<<<256, 256, 0, stream>>>(WY, ST);
  bn_apply<<<8192, 256, 0, stream>>>(WY, x, ST, gamma, beta, out);
}

// Round 6
// 255.247 us; speedup vs baseline: 1.1282x; 1.1282x over previous
//
#include <hip/hip_runtime.h>
#include <hip/hip_bf16.h>
#include <math.h>

#define B_   8
#define C_   256
#define CI_  128
#define N_   4096

typedef unsigned short ushort_t;
typedef unsigned int uint_t;
typedef __attribute__((ext_vector_type(8))) short short8;
typedef __attribute__((ext_vector_type(16))) float floatx16;

// workspace layout (byte offsets)
#define OFF_W3B  0ull           // bf16 [384][256]
#define OFF_B3   196608ull      // fp32 [384]
#define OFF_WCB  198144ull      // bf16 [256][128]
#define OFF_XT   263680ull      // bf16 [B][N][256]      16.8 MB
#define OFF_THT  17040896ull    // bf16 [B][N][128]      8.4 MB
#define OFF_PHT  25429504ull    // bf16 [B][N][128]      8.4 MB
#define OFF_G16  33818112ull    // bf16 [B][128][N]      8.4 MB
#define OFF_LP   42206720ull    // fp32 [2][B][N]        256 KB
#define OFF_YPB  42468864ull    // bf16 [2][B][N][128]   16.8 MB
#define OFF_WY   263680ull      // fp32 [B][256][N] — aliases XT/THT/PHT (dead by wgemm)
#define OFF_ST   59246080ull    // fp32 [2][256]
// total ~59.3 MB

__device__ __forceinline__ ushort_t f2bf(float x) {
  union { float f; uint_t u; } c; c.f = x;
  return (ushort_t)((c.u + 0x7fffu + ((c.u >> 16) & 1u)) >> 16);
}
// packed bf16 convert (v_cvt_pk_bf16_f32 on gfx950): a -> lo, b -> hi
__device__ __forceinline__ uint_t pkbf(float a, float b) {
  __hip_bfloat162 h = __float22bfloat162_rn(float2{a, b});
  union { __hip_bfloat162 h; uint_t u; } c; c.h = h; return c.u;
}
__device__ __forceinline__ float bf_lo(uint_t u) {
  union { uint_t u; float f; } c; c.u = u << 16; return c.f;
}
__device__ __forceinline__ float bf_hi(uint_t u) {
  union { uint_t u; float f; } c; c.u = u & 0xffff0000u; return c.f;
}
__device__ __forceinline__ void async_copy16(const void* g, void* l) {
  __builtin_amdgcn_global_load_lds(
      (const __attribute__((address_space(1))) unsigned int*)g,
      (__attribute__((address_space(3))) unsigned int*)l, 16, 0, 0);
}

// -------- pack all weights: W3b bf16 [384][256], b3 fp32, Wc bf16 [256][128] -
__global__ __launch_bounds__(256) void pack_w(
    const float* __restrict__ g_w, const float* __restrict__ g_b,
    const float* __restrict__ th_w, const float* __restrict__ th_b,
    const float* __restrict__ ph_w, const float* __restrict__ ph_b,
    const float* __restrict__ W_w,
    ushort_t* __restrict__ W3b, float* __restrict__ b3,
    ushort_t* __restrict__ Wc)
{
  int bid = blockIdx.x;
  if (bid < 384) {
    int i = bid * 256 + threadIdx.x;
    int o = i >> 8;
    float v;
    if (o < 128)      v = g_w[i];
    else if (o < 256) v = th_w[i - 128*256];
    else              v = ph_w[i - 256*256];
    W3b[i] = f2bf(v);
    if ((i & 255) == 0)
      b3[o] = (o < 128) ? g_b[o] : (o < 256) ? th_b[o - 128] : ph_b[o - 256];
  } else {
    int j = (bid - 384) * 256 + threadIdx.x;   // < 32768
    Wc[j] = f2bf(W_w[j]);
  }
}

// -------- x [b][c][n] fp32 -> xt [b][n][c] bf16 (64x64 LDS transpose) -------
__global__ __launch_bounds__(256) void xcast(
    const float* __restrict__ x, ushort_t* __restrict__ xt)
{
  const int b = blockIdx.z, c0 = blockIdx.y * 64, n0 = blockIdx.x * 64;
  const int tid = threadIdx.x;
  __shared__ float xs[64][65];
  const int nq = (tid & 15) * 4, cr = tid >> 4;
  #pragma unroll
  for (int i = 0; i < 4; ++i) {
    float4 v = *(const float4*)&x[((size_t)b * C_ + c0 + cr + 16*i) * N_ + n0 + nq];
    xs[cr + 16*i][nq] = v.x; xs[cr + 16*i][nq+1] = v.y;
    xs[cr + 16*i][nq+2] = v.z; xs[cr + 16*i][nq+3] = v.w;
  }
  __syncthreads();
  const int n = tid >> 2, cs = (tid & 3) * 16;
  uint_t u[8];
  #pragma unroll
  for (int j = 0; j < 8; ++j)
    u[j] = pkbf(xs[cs + 2*j][n], xs[cs + 2*j + 1][n]);
  ushort_t* dst = &xt[((size_t)b * N_ + n0 + n) * C_ + c0 + cs];
  *(uint4*)dst       = make_uint4(u[0], u[1], u[2], u[3]);
  *(uint4*)(dst + 8) = make_uint4(u[4], u[5], u[6], u[7]);
}

// -------- projection GEMM, bf16 MFMA 32x32x16, all 3 outputs in one launch --
// blockIdx.y: 0 -> theta^T, 1 -> phi^T (C rows=o cols=n), 2 -> g (C rows=n cols=o)
__global__ __launch_bounds__(256, 2) void proj_all(
    const ushort_t* __restrict__ W3b, const float* __restrict__ b3,
    const ushort_t* __restrict__ xt, ushort_t* __restrict__ tht,
    ushort_t* __restrict__ pht, ushort_t* __restrict__ g16)
{
  const int b = blockIdx.z, nb = blockIdx.x, ot = blockIdx.y;
  const int gm = (ot == 2);
  const int o0 = gm ? 0 : (128 + ot * 128);
  const int tid = threadIdx.x, w = tid >> 6, lane = tid & 63;
  const int l31 = lane & 31, h = lane >> 5, xk = l31 & 7;
  __shared__ ushort_t ws_l[128 * 64];
  __shared__ ushort_t xs_l[128 * 64];
  const ushort_t* xb = xt + (size_t)b * N_ * C_;
  const int n0 = nb * 128;
  floatx16 acc[4];
  #pragma unroll
  for (int ct = 0; ct < 4; ++ct)
    #pragma unroll
    for (int r = 0; r < 16; ++r) acc[ct][r] = 0.f;

  const int gr = lane >> 3, gu = lane & 7;
  for (int k0 = 0; k0 < C_; k0 += 64) {
    __syncthreads();
    #pragma unroll
    for (int i = 0; i < 4; ++i) {
      int r = w*32 + i*8 + gr;
      async_copy16(&W3b[(size_t)(o0 + r) * C_ + k0 + ((gu ^ (r & 7)) * 8)],
                   &ws_l[(w*32 + i*8) * 64]);
      async_copy16(&xb[(size_t)(n0 + r) * C_ + k0 + ((gu ^ (r & 7)) * 8)],
                   &xs_l[(w*32 + i*8) * 64]);
    }
    __syncthreads();
    const ushort_t* bmat = gm ? ws_l : xs_l;
    const ushort_t* amat = gm ? xs_l : ws_l;
    #pragma unroll
    for (int kk = 0; kk < 4; ++kk) {
      int fc = ((2*kk + h) ^ xk) * 8;
      short8 bf = *(const short8*)&bmat[(w*32 + l31) * 64 + fc];
      #pragma unroll
      for (int ct = 0; ct < 4; ++ct) {
        short8 af = *(const short8*)&amat[(ct*32 + l31) * 64 + fc];
        acc[ct] = __builtin_amdgcn_mfma_f32_32x32x16_bf16(af, bf, acc[ct], 0, 0, 0);
      }
    }
  }

  if (gm) {
    float bv = b3[w*32 + l31];
    ushort_t* gp = g16 + ((size_t)b * CI_ + w*32 + l31) * N_;
    #pragma unroll
    for (int ct = 0; ct < 4; ++ct)
      #pragma unroll
      for (int rq = 0; rq < 4; ++rq) {
        uint2 d = make_uint2(pkbf(acc[ct][4*rq+0] + bv, acc[ct][4*rq+1] + bv),
                             pkbf(acc[ct][4*rq+2] + bv, acc[ct][4*rq+3] + bv));
        *(uint2*)&gp[n0 + ct*32 + 8*rq + 4*h] = d;
      }
  } else {
    ushort_t* tp = ((ot == 0) ? tht : pht) + ((size_t)b * N_ + n0 + w*32 + l31) * CI_;
    #pragma unroll
    for (int ct = 0; ct < 4; ++ct)
      #pragma unroll
      for (int rq = 0; rq < 4; ++rq) {
        float4 bv = *(const float4*)&b3[o0 + ct*32 + 8*rq + 4*h];
        uint2 d = make_uint2(pkbf(acc[ct][4*rq+0] + bv.x, acc[ct][4*rq+1] + bv.y),
                             pkbf(acc[ct][4*rq+2] + bv.z, acc[ct][4*rq+3] + bv.w));
        *(uint2*)&tp[ct*32 + 8*rq + 4*h] = d;
      }
  }
}

// ---------------------------------------------------------------------------
// MFMA flash attention (round-4 proven loop): 1 q-tile/wave, 4 waves = 128 q
// per block, 48 KB LDS -> 2 blocks/CU. Grid 512 = qb(32) x ms(2) x b(8).
// Epilogue: in-LDS transpose -> bf16 partials yp[ms][b][q][c] (wgemm-ready).
// ---------------------------------------------------------------------------
#define LOG2E_  1.442695041f
#define MBIAS_  (-28.85390082f)   /* = -20 * log2(e) */

__global__ __launch_bounds__(256, 2) void attn_mfma(
    const ushort_t* __restrict__ tht, const ushort_t* __restrict__ pht,
    const ushort_t* __restrict__ g16, ushort_t* __restrict__ yp,
    float* __restrict__ lp)
{
  const int b  = blockIdx.x & 7;           // batch -> XCD
  const int ms = (blockIdx.x >> 3) & 1;    // key split
  const int qb = blockIdx.x >> 4;          // 0..31
  const int tid = threadIdx.x, w = tid >> 6, lane = tid & 63;
  const int l31 = lane & 31, h = lane >> 5, xk = l31 & 7;

  // smem (ushort idx): phs @0 (64x128), gs @8192 (128x64), Pl @16384+w*2048
  __shared__ ushort_t smem[24576];   // 48 KB
  ushort_t* phs = smem;
  ushort_t* gs  = smem + 8192;
  ushort_t* Plw = smem + 16384 + w * 2048;

  const int q0w = qb * 128 + w * 32;
  const int m_base = ms * 2048;

  const ushort_t* thb = tht + (size_t)b * N_ * CI_;
  const ushort_t* phb = pht + (size_t)b * N_ * CI_;
  const ushort_t* gbp = g16 + (size_t)b * CI_ * N_;

  // theta B-frags (lane: col q = l31, k contig), register-resident
  short8 tf[8];
  #pragma unroll
  for (int kk = 0; kk < 8; ++kk)
    tf[kk] = *(const short8*)&thb[(size_t)(q0w + l31) * CI_ + kk*16 + h*8];

  floatx16 acc[4];
  #pragma unroll
  for (int ct = 0; ct < 4; ++ct)
    #pragma unroll
    for (int r = 0; r < 16; ++r) acc[ct][r] = 0.f;
  float lpart = 0.f;

  const int phr = lane >> 4, phu = lane & 15;
  const int gr  = lane >> 3, gu  = lane & 7;

  for (int m0 = m_base; m0 < m_base + 2048; m0 += 64) {
    __syncthreads();   // prior iter's LDS readers done
    #pragma unroll
    for (int i = 0; i < 4; ++i) {
      int row = w*16 + i*4 + phr;
      async_copy16(&phb[(size_t)(m0 + row) * CI_ + ((phu ^ (row & 7)) * 8)],
                   &phs[(w*16 + i*4) * 128]);
    }
    #pragma unroll
    for (int i = 0; i < 4; ++i) {
      int c = w*32 + i*8 + gr;
      async_copy16(&gbp[(size_t)c * N_ + m0 + ((gu ^ (c & 7)) * 8)],
                   &gs[(w*32 + i*8) * 64]);
    }
    __syncthreads();   // staging visible

    // QK^T + exp + P pack (lane = col q fixed -> softmax lane-local)
    #pragma unroll
    for (int mt = 0; mt < 2; ++mt) {
      floatx16 s;
      #pragma unroll
      for (int r = 0; r < 16; ++r) s[r] = 0.f;
      #pragma unroll
      for (int kk = 0; kk < 8; ++kk) {
        short8 pf = *(const short8*)&phs[(mt*32 + l31) * 128 + (((2*kk + h) ^ xk) * 8)];
        s = __builtin_amdgcn_mfma_f32_32x32x16_bf16(pf, tf[kk], s, 0, 0, 0);
      }
      float ls = 0.f;
      #pragma unroll
      for (int rq = 0; rq < 4; ++rq) {
        float p0 = exp2f(fmaf(s[4*rq+0], LOG2E_, MBIAS_));
        float p1 = exp2f(fmaf(s[4*rq+1], LOG2E_, MBIAS_));
        float p2 = exp2f(fmaf(s[4*rq+2], LOG2E_, MBIAS_));
        float p3 = exp2f(fmaf(s[4*rq+3], LOG2E_, MBIAS_));
        ls += (p0 + p1) + (p2 + p3);
        uint2 d = make_uint2(pkbf(p0, p1), pkbf(p2, p3));
        *(uint2*)&Plw[l31 * 64 + (((mt*4 + rq) ^ xk) * 8) + h*4] = d;
      }
      lpart += ls;
    }

    // PV: y^T[c][q] += g[c][m] . P[m][q]  (P wave-private: same-wave ordering)
    #pragma unroll
    for (int kk = 0; kk < 4; ++kk) {
      int pc = ((2*kk + h) ^ xk) * 8;
      short8 pfr = *(const short8*)&Plw[l31 * 64 + pc];
      #pragma unroll
      for (int ct = 0; ct < 4; ++ct) {
        short8 gf = *(const short8*)&gs[(ct*32 + l31) * 64 + pc];
        acc[ct] = __builtin_amdgcn_mfma_f32_32x32x16_bf16(gf, pfr, acc[ct], 0, 0, 0);
      }
    }
  }

  // partial l
  float lq = lpart + __shfl_xor(lpart, 32);
  if (h == 0)
    lp[((size_t)ms * 8 + b) * N_ + q0w + l31] = lq;

  // epilogue: in-LDS transpose (wave region 8 KB) -> bf16 [q][c] partials
  __syncthreads();   // all waves done with phs/gs before overwrite
  ushort_t* tr = smem + w * 4096;   // 32 rows(q) x 128 (c)
  #pragma unroll
  for (int ct = 0; ct < 4; ++ct)
    #pragma unroll
    for (int rq = 0; rq < 4; ++rq) {
      uint2 d = make_uint2(pkbf(acc[ct][4*rq+0], acc[ct][4*rq+1]),
                           pkbf(acc[ct][4*rq+2], acc[ct][4*rq+3]));
      *(uint2*)&tr[l31 * 128 + ct*32 + 8*rq + 4*h] = d;
    }
  // same-wave LDS write->read: no barrier needed
  ushort_t* ypb = yp + (((size_t)ms * 8 + b) * N_ + q0w) * CI_;
  #pragma unroll
  for (int itx = 0; itx < 8; ++itx) {
    int row = itx*4 + (lane >> 4);
    int cu  = (lane & 15) * 8;
    uint4 v = *(const uint4*)&tr[row * 128 + cu];
    *(uint4*)&ypb[(size_t)row * CI_ + cu] = v;
  }
}

// -------- W-conv GEMM with fused combine: ----------------------------------
// WY[b][o][n] = sum_c Wc[o][c] * [ (yp0[n][c]+yp1[n][c]) / (l0[n]+l1[n]) ] + Wb[o]
__global__ __launch_bounds__(256, 2) void wgemm_fused(
    const ushort_t* __restrict__ Wc, const float* __restrict__ Wb,
    const ushort_t* __restrict__ yp, const float* __restrict__ lp,
    float* __restrict__ WY)
{
  const int b = blockIdx.z, nb = blockIdx.x, ot = blockIdx.y;
  const int o0 = ot * 128;
  const int tid = threadIdx.x, w = tid >> 6, lane = tid & 63;
  const int l31 = lane & 31, h = lane >> 5, xk = l31 & 7;
  __shared__ ushort_t ws_l[128 * 64];
  __shared__ ushort_t xs_l[128 * 64];
  const int n0 = nb * 128;
  const size_t PH = (size_t)B_ * N_ * CI_;
  const ushort_t* yp0 = yp + (size_t)b * N_ * CI_;
  const ushort_t* yp1 = yp0 + PH;
  floatx16 acc[4];
  #pragma unroll
  for (int ct = 0; ct < 4; ++ct)
    #pragma unroll
    for (int r = 0; r < 16; ++r) acc[ct][r] = 0.f;

  const int gr = lane >> 3, gu = lane & 7;
  for (int k0 = 0; k0 < CI_; k0 += 64) {
    __syncthreads();
    #pragma unroll
    for (int i = 0; i < 4; ++i) {
      int r = w*32 + i*8 + gr;
      async_copy16(&Wc[(size_t)(o0 + r) * CI_ + k0 + ((gu ^ (r & 7)) * 8)],
                   &ws_l[(w*32 + i*8) * 64]);
      // fused combine staging: y = (yp0 + yp1) * inv(l0+l1), bf16 -> LDS
      int n = n0 + r;
      size_t src = (size_t)n * CI_ + k0 + ((gu ^ (r & 7)) * 8);
      uint4 a0 = *(const uint4*)&yp0[src];
      uint4 a1 = *(const uint4*)&yp1[src];
      float inv = 1.0f / (lp[(size_t)b * N_ + n] + lp[(size_t)(8 + b) * N_ + n]);
      uint4 o;
      o.x = pkbf((bf_lo(a0.x) + bf_lo(a1.x)) * inv, (bf_hi(a0.x) + bf_hi(a1.x)) * inv);
      o.y = pkbf((bf_lo(a0.y) + bf_lo(a1.y)) * inv, (bf_hi(a0.y) + bf_hi(a1.y)) * inv);
      o.z = pkbf((bf_lo(a0.z) + bf_lo(a1.z)) * inv, (bf_hi(a0.z) + bf_hi(a1.z)) * inv);
      o.w = pkbf((bf_lo(a0.w) + bf_lo(a1.w)) * inv, (bf_hi(a0.w) + bf_hi(a1.w)) * inv);
      *(uint4*)&xs_l[r * 64 + gu * 8] = o;
    }
    __syncthreads();
    #pragma unroll
    for (int kk = 0; kk < 4; ++kk) {
      int fc = ((2*kk + h) ^ xk) * 8;
      short8 bf = *(const short8*)&xs_l[(w*32 + l31) * 64 + fc];
      #pragma unroll
      for (int ct = 0; ct < 4; ++ct) {
        short8 af = *(const short8*)&ws_l[(ct*32 + l31) * 64 + fc];
        acc[ct] = __builtin_amdgcn_mfma_f32_32x32x16_bf16(af, bf, acc[ct], 0, 0, 0);
      }
    }
  }
  const int n = n0 + w*32 + l31;
  #pragma unroll
  for (int ct = 0; ct < 4; ++ct)
    #pragma unroll
    for (int rq = 0; rq < 4; ++rq) {
      float4 bv = *(const float4*)&Wb[o0 + ct*32 + 8*rq + 4*h];
      #pragma unroll
      for (int j = 0; j < 4; ++j) {
        int o = o0 + ct*32 + 8*rq + 4*h + j;
        WY[((size_t)b * C_ + o) * N_ + n] = acc[ct][4*rq + j] + (&bv.x)[j];
      }
    }
}

__global__ __launch_bounds__(256) void bn_stats(
    const float* __restrict__ WY, float* __restrict__ st)
{
  const int o = blockIdx.x;
  const int tid = threadIdx.x;
  float s = 0.f, s2 = 0.f;
  for (int b = 0; b < B_; ++b) {
    const float* p = WY + ((size_t)b * C_ + o) * N_;
    for (int n = tid * 4; n < N_; n += 256 * 4) {
      float4 v = *(const float4*)&p[n];
      s  += v.x + v.y + v.z + v.w;
      s2 += v.x * v.x + v.y * v.y + v.z * v.z + v.w * v.w;
    }
  }
  __shared__ float rs[256], rs2[256];
  rs[tid] = s; rs2[tid] = s2;
  __syncthreads();
  for (int off = 128; off > 0; off >>= 1) {
    if (tid < off) { rs[tid] += rs[tid + off]; rs2[tid] += rs2[tid + off]; }
    __syncthreads();
  }
  if (tid == 0) {
    const float M = (float)(B_ * N_);
    float mean = rs[0] / M;
    float var  = rs2[0] / M - mean * mean;
    st[o] = mean;
    st[256 + o] = rsqrtf(var + 1e-5f);
  }
}

__global__ __launch_bounds__(256) void bn_apply(
    const float* __restrict__ WY, const float* __restrict__ x,
    const float* __restrict__ st, const float* __restrict__ gamma,
    const float* __restrict__ beta, float* __restrict__ out)
{
  size_t i = ((size_t)blockIdx.x * 256 + threadIdx.x) * 4;
  int o = (int)((i >> 12) & 255);
  float4 w  = *(const float4*)&WY[i];
  float4 xv = *(const float4*)&x[i];
  float gsc = gamma[o] * st[256 + o];
  float bb  = beta[o] - st[o] * gsc;
  float4 v;
  v.x = w.x * gsc + bb + xv.x;
  v.y = w.y * gsc + bb + xv.y;
  v.z = w.z * gsc + bb + xv.z;
  v.w = w.w * gsc + bb + xv.w;
  *(float4*)&out[i] = v;
}

extern "C" void kernel_launch(void* const* d_in, const int* in_sizes, int n_in,
                              void* d_out, int out_size, void* d_ws, size_t ws_size,
                              hipStream_t stream)
{
  const float* x       = (const float*)d_in[0];
  const float* g_w     = (const float*)d_in[1];
  const float* g_b     = (const float*)d_in[2];
  const float* theta_w = (const float*)d_in[3];
  const float* theta_b = (const float*)d_in[4];
  const float* phi_w   = (const float*)d_in[5];
  const float* phi_b   = (const float*)d_in[6];
  const float* W_w     = (const float*)d_in[7];
  const float* W_b     = (const float*)d_in[8];
  const float* gamma   = (const float*)d_in[9];
  const float* beta    = (const float*)d_in[10];
  float* out = (float*)d_out;

  char* ws = (char*)d_ws;
  ushort_t* W3b = (ushort_t*)(ws + OFF_W3B);
  float*    b3  = (float*)(ws + OFF_B3);
  ushort_t* Wc  = (ushort_t*)(ws + OFF_WCB);
  ushort_t* xt  = (ushort_t*)(ws + OFF_XT);
  ushort_t* tht = (ushort_t*)(ws + OFF_THT);
  ushort_t* pht = (ushort_t*)(ws + OFF_PHT);
  ushort_t* g16 = (ushort_t*)(ws + OFF_G16);
  float*    lpp = (float*)(ws + OFF_LP);
  ushort_t* ypb = (ushort_t*)(ws + OFF_YPB);
  float*    WY  = (float*)(ws + OFF_WY);    // aliases XT/THT/PHT (dead by wgemm)
  float*    ST  = (float*)(ws + OFF_ST);

  pack_w<<<512, 256, 0, stream>>>(g_w, g_b, theta_w, theta_b, phi_w, phi_b,
                                  W_w, W3b, b3, Wc);
  xcast<<<dim3(64, 4, 8), 256, 0, stream>>>(x, xt);
  proj_all<<<dim3(32, 3, 8), 256, 0, stream>>>(W3b, b3, xt, tht, pht, g16);
  attn_mfma<<<512, 256, 0, stream>>>(tht, pht, g16, ypb, lpp);
  wgemm_fused<<<dim3(32, 2, 8), 256, 0, stream>>>(Wc, W_b, ypb, lpp, WY);
  bn_stats<<<256, 256, 0, stream>>>(WY, ST);
  bn_apply<<<8192, 256, 0, stream>>>(WY, x, ST, gamma, beta, out);
}